// Round 14
// baseline (23485.942 us; speedup 1.0000x reference)
//
#include <hip/hip_runtime.h>
#include <cstdint>
#include <cstddef>

#define T_LEN 8192
#define EMB 256
#define HD 256          // hidden per direction
#define G4 1024         // 4*HD
#define NT 16
#define START_IX 14
#define STOP_IX 15

#define SLICE 8         // h outputs per WG per direction
#define ROWSD 32        // gate rows per WG per direction (4 gates x 8)
#define WPAD 260        // 1040B row stride: b128-legal + bank-balanced
#define SENT 0xFFFFFFFFu

// mbox slot: [dir][parity][producer][j]
#define MB(d, p, s, j) ((((size_t)(d) * 2 + (p)) * 32 + (s)) * 8 + (j))

// ---------------------------------------------------------------------------
// shared-memory union: scan state vs gemm staging (different block roles)
// ---------------------------------------------------------------------------
struct ScanS {
    float wf[ROWSD * WPAD];   // fwd weights (33280 B)
    float wb[ROWSD * WPAD];   // bwd weights
    float hf[256];
    float hb[256];
    float part[ROWSD * 17];   // partial[r][q], 17-pad -> conflict-free columns
    float xwr[16][2][32];     // xw ring: [step%16][dir][row] (4 KB)
};
struct GemmS {
    float at[32][65];
    float bt[128][65];
};
#define SMEM_BYTES 83968   // > 81920 -> exactly 1 block/CU (256 blocks = 256 CUs)

// ---------------------------------------------------------------------------
// Dual-path poll, fast-first (r14): 3 fast probes per slow probe. FAST =
// sc0 load of step-tagged mbox packet, served by the local XCD L2 under the
// blockIdx%8 co-location (proven live by r10's 223->62GB FETCH collapse).
// SLOW (proven r2-r13) = relaxed agent load of the sentinel h word -- now
// only every 4th miss, so its ~900cy MALL RTT is off the common path.
// Any hit is THE value; wrong placement only delays, never corrupts.
// ---------------------------------------------------------------------------
__device__ __forceinline__ unsigned poll_dual(
    const unsigned long long* __restrict__ fsrc,
    const unsigned* __restrict__ ssrc, unsigned t)
{
#pragma unroll 1
    for (int it = 0; it < (1 << 20); ++it) {
        unsigned long long u;
        asm volatile("global_load_dwordx2 %0, %1, off sc0\n\t"
                     "s_waitcnt vmcnt(0)"
                     : "=v"(u) : "v"(fsrc) : "memory");
        if ((unsigned)(u >> 32) == t) return (unsigned)u;
        if ((it & 3) == 3) {
            unsigned v = __hip_atomic_load(ssrc, __ATOMIC_RELAXED,
                                           __HIP_MEMORY_SCOPE_AGENT);
            if (v != SENT) return v;
        }
    }
    return 0u;   // unreachable in practice (slow path is proven)
}

// sentinel poll of a once-written word (xw; written by gemm filler blocks)
__device__ __forceinline__ unsigned poll_sent(const unsigned* p) {
    unsigned v; int spin = 0;
    do {
        v = __hip_atomic_load(p, __ATOMIC_RELAXED, __HIP_MEMORY_SCOPE_AGENT);
    } while (v == SENT && ++spin < (1 << 20));
    return v;
}

// ---------------------------------------------------------------------------
// Fused kernel. grid 256, block 512.  (r13 structure, unchanged except
// poll_dual above.)
//  blockIdx%8 == 0 -> scan block, wsl = blockIdx>>3 (0..31): fwd+bwd slice
//  blockIdx%8 != 0 -> gemm filler computing xw
// Scan iteration (r11's proven 4-phase alternation; r12 proved co-phasing
// produce and poll exposes full exchange latency):
//   A: mv_f(t) | B1 | B: produce_f(t) & poll h_b(t-1) & [t%8==0: bulk xw
//      prefetch t+8..t+15] | B2 | C: mv_b(t) | B3 | D: produce_b(t) &
//      poll h_f(t) | B4
// ---------------------------------------------------------------------------
__global__ __launch_bounds__(512) void k_fused(
    const int* __restrict__ sent, const float* __restrict__ embed,
    const float* __restrict__ wih_f, const float* __restrict__ wih_b,
    const float* __restrict__ bih_f, const float* __restrict__ bhh_f,
    const float* __restrict__ bih_b, const float* __restrict__ bhh_b,
    const float* __restrict__ whh_f, const float* __restrict__ whh_b,
    const float* __restrict__ h0, const float* __restrict__ c0,
    float* __restrict__ xw, float* __restrict__ h_hist,
    unsigned long long* __restrict__ mbox)
{
    __shared__ __align__(16) char smraw[SMEM_BYTES];
    const int tid = threadIdx.x;

    if ((blockIdx.x & 7) != 0) {
        // ================= gemm filler =================
        GemmS* G = (GemmS*)smraw;
        const int f = (blockIdx.x >> 3) * 7 + (blockIdx.x & 7) - 1;  // 0..223
        const int tx = tid & 31, ty = tid >> 5;                      // 32 x 16
        for (int u = f; u < 4096; u += 224) {
            const int t_tile = u >> 4, sub = u & 15;
            const int dir = sub >> 3, r_tile = sub & 7;
            const float* __restrict__ wih = dir ? wih_b : wih_f;
            const float* __restrict__ bih = dir ? bih_b : bih_f;
            const float* __restrict__ bhh = dir ? bhh_b : bhh_f;
            const int t0 = t_tile * 32, r0 = r_tile * 128;
            float acc[2][4] = {};
            for (int k0 = 0; k0 < EMB; k0 += 64) {
                __syncthreads();   // protect staging buffers
                for (int i = tid; i < 32 * 64; i += 512) {
                    int row = i >> 6, k = i & 63;
                    int t = t0 + row;
                    int ts = dir ? (T_LEN - 1 - t) : t;
                    G->at[row][k] = embed[(size_t)sent[ts] * EMB + k0 + k];
                }
                for (int i = tid; i < 128 * 64; i += 512) {
                    int row = i >> 6, k = i & 63;
                    G->bt[row][k] = wih[(size_t)(r0 + row) * EMB + k0 + k];
                }
                __syncthreads();
#pragma unroll 16
                for (int kc = 0; kc < 64; ++kc) {
                    float a[2], b[4];
#pragma unroll
                    for (int v = 0; v < 2; ++v) a[v] = G->at[ty * 2 + v][kc];
#pragma unroll
                    for (int v = 0; v < 4; ++v) b[v] = G->bt[tx * 4 + v][kc];
#pragma unroll
                    for (int v = 0; v < 2; ++v)
#pragma unroll
                        for (int w = 0; w < 4; ++w) acc[v][w] += a[v] * b[w];
                }
            }
#pragma unroll
            for (int v = 0; v < 2; ++v) {
                int t = t0 + ty * 2 + v;
#pragma unroll
                for (int w = 0; w < 4; ++w) {
                    int r = r0 + tx * 4 + w;
                    float val = acc[v][w] + bih[r] + bhh[r];
                    __hip_atomic_store(
                        (unsigned*)&xw[((size_t)dir * T_LEN + t) * G4 + r],
                        __float_as_uint(val),
                        __ATOMIC_RELAXED, __HIP_MEMORY_SCOPE_AGENT);
                }
            }
        }
        return;
    }

    // ================= scan block =================
    ScanS* S = (ScanS*)smraw;
    const int wsl = blockIdx.x >> 3;      // 0..31
    const int wave = tid >> 6, lane = tid & 63;

    // stage both directions' weights once (33 KB each)
    for (int i = tid; i < ROWSD * 256; i += 512) {
        int r = i >> 8, k = i & 255;
        int R = ((r >> 3) << 8) + wsl * SLICE + (r & 7);
        S->wf[r * WPAD + k] = whh_f[(size_t)R * HD + k];
        S->wb[r * WPAD + k] = whh_b[(size_t)R * HD + k];
    }
    if (tid < 256) { S->hf[tid] = h0[tid]; S->hb[tid] = h0[256 + tid]; }
    float c_f = 0.f, c_b = 0.f;
    if (wave == 0 && lane < 8) {
        c_f = c0[wsl * SLICE + lane];
        c_b = c0[256 + wsl * SLICE + lane];
    }
    // xw ring init: steps 0..7 via proven agent poll (gemm runs concurrently)
    if (tid < 512) {
        int s = tid >> 6, e = tid & 63, d = e >> 5, row = e & 31;
        int R = ((row >> 3) << 8) + wsl * SLICE + (row & 7);
        unsigned v = poll_sent(
            (const unsigned*)&xw[((size_t)d * T_LEN + s) * G4 + R]);
        S->xwr[s][d][row] = __uint_as_float(v);
    }
    __syncthreads();

    float* __restrict__ hhf = h_hist;
    float* __restrict__ hhb = h_hist + (size_t)T_LEN * HD;

    for (int t = 0; t < T_LEN; ++t) {
        const int cur = t & 1;

        // ---- A: mv_f. thread (q=tid>>5 k-seg 0..15, rr=tid&31), b128 ----
        {
            const int q = tid >> 5, rr = tid & 31;
            const float4* wr = (const float4*)&S->wf[rr * WPAD + q * 16];
            const float4* hp = (const float4*)&S->hf[q * 16];
            float a0 = 0.f, a1 = 0.f, a2 = 0.f, a3 = 0.f;
#pragma unroll
            for (int i = 0; i < 4; ++i) {
                float4 wv = wr[i], hv = hp[i];
                a0 += wv.x * hv.x; a1 += wv.y * hv.y;
                a2 += wv.z * hv.z; a3 += wv.w * hv.w;
            }
            S->part[rr * 17 + q] = (a0 + a1) + (a2 + a3);
        }
        __syncthreads();   // B1

        if (wave == 0) {
            // ---- produce_f ----
            const int r = lane & 31;
            float xwv = S->xwr[t & 15][0][r];
            if (__builtin_amdgcn_ballot_w64(__float_as_uint(xwv) == SENT)) {
                int R = ((r >> 3) << 8) + wsl * SLICE + (r & 7);
                xwv = __uint_as_float(poll_sent(
                    (const unsigned*)&xw[(size_t)t * G4 + R]));
            }
            float z = xwv;
#pragma unroll
            for (int q = 0; q < 16; ++q) z += S->part[r * 17 + q];
            float a = ((r >> 3) == 2) ? tanhf(z) : 1.f / (1.f + expf(-z));
            const int j = r & 7;
            float af = __shfl(a, 8 + j);
            float ag = __shfl(a, 16 + j);
            float ao = __shfl(a, 24 + j);
            if (lane < 8) {
                c_f = af * c_f + a * ag;
                float hv = ao * tanhf(c_f);
                S->hf[wsl * SLICE + j] = hv;
                unsigned long long pkt =
                    ((unsigned long long)(unsigned)t << 32)
                    | (unsigned long long)__float_as_uint(hv);
                mbox[MB(0, cur, wsl, j)] = pkt;          // fast (plain -> L2)
                __hip_atomic_store(
                    (unsigned*)&hhf[(size_t)t * HD + wsl * SLICE + j],
                    __float_as_uint(hv),
                    __ATOMIC_RELAXED, __HIP_MEMORY_SCOPE_AGENT);
            }
        } else if (wave <= 4) {
            if (t > 0) {   // gather h_b(t-1), stored prev iter phase D
                const int idx = (wave - 1) * 64 + lane;   // 0..255
                if ((idx >> 3) != wsl) {
                    unsigned v = poll_dual(
                        &mbox[MB(1, (t - 1) & 1, idx >> 3, idx & 7)],
                        (const unsigned*)&hhb[(size_t)(t - 1) * HD + idx],
                        (unsigned)(t - 1));
                    S->hb[idx] = __uint_as_float(v);
                }
            }
        } else if (wave <= 6) {
            // bulk xw prefetch: every 8th iter, steps t+8..t+15 (plain loads,
            // drained at B2; benign-stale + sentinel-checked at consumption)
            if ((t & 7) == 0 && t + 8 < T_LEN) {
                const int base = (wave - 5) * 64 + lane;  // 0..127
#pragma unroll
                for (int u = 0; u < 4; ++u) {
                    int item = base + u * 128;            // 0..511
                    int s = item >> 6, e = item & 63;
                    int d = e >> 5, row = e & 31;
                    int step = t + 8 + s;
                    int R = ((row >> 3) << 8) + wsl * SLICE + (row & 7);
                    S->xwr[step & 15][d][row] =
                        xw[((size_t)d * T_LEN + step) * G4 + R];
                }
            }
        }
        __syncthreads();   // B2

        // ---- C: mv_b ----
        {
            const int q = tid >> 5, rr = tid & 31;
            const float4* wr = (const float4*)&S->wb[rr * WPAD + q * 16];
            const float4* hp = (const float4*)&S->hb[q * 16];
            float a0 = 0.f, a1 = 0.f, a2 = 0.f, a3 = 0.f;
#pragma unroll
            for (int i = 0; i < 4; ++i) {
                float4 wv = wr[i], hv = hp[i];
                a0 += wv.x * hv.x; a1 += wv.y * hv.y;
                a2 += wv.z * hv.z; a3 += wv.w * hv.w;
            }
            S->part[rr * 17 + q] = (a0 + a1) + (a2 + a3);
        }
        __syncthreads();   // B3

        if (wave == 0) {
            // ---- produce_b ----
            const int r = lane & 31;
            float xwv = S->xwr[t & 15][1][r];
            if (__builtin_amdgcn_ballot_w64(__float_as_uint(xwv) == SENT)) {
                int R = ((r >> 3) << 8) + wsl * SLICE + (r & 7);
                xwv = __uint_as_float(poll_sent((const unsigned*)
                    &xw[((size_t)T_LEN + t) * G4 + R]));
            }
            float z = xwv;
#pragma unroll
            for (int q = 0; q < 16; ++q) z += S->part[r * 17 + q];
            float a = ((r >> 3) == 2) ? tanhf(z) : 1.f / (1.f + expf(-z));
            const int j = r & 7;
            float af = __shfl(a, 8 + j);
            float ag = __shfl(a, 16 + j);
            float ao = __shfl(a, 24 + j);
            if (lane < 8) {
                c_b = af * c_b + a * ag;
                float hv = ao * tanhf(c_b);
                S->hb[wsl * SLICE + j] = hv;
                unsigned long long pkt =
                    ((unsigned long long)(unsigned)t << 32)
                    | (unsigned long long)__float_as_uint(hv);
                mbox[MB(1, cur, wsl, j)] = pkt;
                __hip_atomic_store(
                    (unsigned*)&hhb[(size_t)t * HD + wsl * SLICE + j],
                    __float_as_uint(hv),
                    __ATOMIC_RELAXED, __HIP_MEMORY_SCOPE_AGENT);
            }
        } else if (wave <= 4) {
            // gather h_f(t), stored this iter phase B (~2 phases earlier)
            const int idx = (wave - 1) * 64 + lane;
            if ((idx >> 3) != wsl) {
                unsigned v = poll_dual(
                    &mbox[MB(0, cur, idx >> 3, idx & 7)],
                    (const unsigned*)&hhf[(size_t)t * HD + idx], (unsigned)t);
                S->hf[idx] = __uint_as_float(v);
            }
        }
        __syncthreads();   // B4
    }
}

// ---------------------------------------------------------------------------
// Phase C: feats. 4-way tag split, 128 WGs. W_out staged in LDS.
// ---------------------------------------------------------------------------
__global__ __launch_bounds__(256) void k_feats(
    const float* __restrict__ h_hist, const float* __restrict__ Wout,
    const float* __restrict__ bout, float* __restrict__ feats)
{
    __shared__ float wlds[16][512];
    const int tid = threadIdx.x;
    for (int i = tid; i < 16 * 512; i += 256) wlds[i >> 9][i & 511] = Wout[i];
    __syncthreads();
    const int idx = blockIdx.x * 256 + tid;          // 0..32767
    const int t = idx >> 2, tg = (idx & 3) * 4;      // 4 tags per thread
    const float4* hf = (const float4*)(h_hist + (size_t)t * HD);
    const float4* hb = (const float4*)(h_hist + (size_t)(T_LEN + (T_LEN - 1 - t)) * HD);
    float acc[4];
#pragma unroll
    for (int g = 0; g < 4; ++g) acc[g] = bout[tg + g];
    for (int k = 0; k < 64; ++k) {
        float4 a = hf[k];
#pragma unroll
        for (int g = 0; g < 4; ++g) {
            float4 b = *(const float4*)&wlds[tg + g][k * 4];
            acc[g] += a.x * b.x + a.y * b.y + a.z * b.z + a.w * b.w;
        }
    }
    for (int k = 0; k < 64; ++k) {
        float4 a = hb[k];
#pragma unroll
        for (int g = 0; g < 4; ++g) {
            float4 b = *(const float4*)&wlds[tg + g][256 + k * 4];
            acc[g] += a.x * b.x + a.y * b.y + a.z * b.z + a.w * b.w;
        }
    }
#pragma unroll
    for (int g = 0; g < 4; ++g) feats[(size_t)t * NT + tg + g] = acc[g];
}

// ---------------------------------------------------------------------------
// Phase D: Viterbi. r14: forward pass in FP32, EXACTLY mirroring the fp32
// reference op-for-op: temp[i,j] = (fv[j] + feat[i]) + trans[i,j];
// fv_new[i] = max_j temp (max is order-exact); bp = FIRST max index.
// Bit-identical rounding to the jnp float32 scan -> same argmax by
// construction, at half the cross-lane cost of the old fp64 chain
// (fp32 shfl = 1 ds_bpermute, f64 = 2; plus full-rate VALU).
// Backtrack: map-composition suffix scan (unchanged, proven).
// ---------------------------------------------------------------------------
__device__ __forceinline__ unsigned bsel16(uint4 g, unsigned e) {
    unsigned wd = (e < 8u) ? ((e < 4u) ? g.x : g.y) : ((e < 12u) ? g.z : g.w);
    return (wd >> ((e & 3u) * 8u)) & 15u;
}

__global__ __launch_bounds__(256) void k_viterbi(
    const float* __restrict__ feats, const float* __restrict__ trans,
    int* __restrict__ out, unsigned char* __restrict__ bp)
{
    __shared__ int sid;
    __shared__ unsigned slo[512], shi[512];
    const int tid = threadIdx.x;

    if (tid < 64) {
        const int i = tid & 15, jg = tid >> 4;
        float tr[4];
#pragma unroll
        for (int u = 0; u < 4; ++u) tr[u] = trans[i * 16 + jg * 4 + u];
        float fvn = (i == START_IX) ? 0.0f : -10000.0f;  // lanes 0-15 live
        float fA = feats[i];
        float fB = feats[16 + i];

        for (int t = 0; t < T_LEN; ++t) {
            float fC = (t + 2 < T_LEN) ? feats[(size_t)(t + 2) * NT + i] : 0.f;

            // temp_u = (fv[j] + f_i) + T[i][j], j = jg*4+u  (exact ref order)
            float best = -3.4e38f; int bj = 0;
#pragma unroll
            for (int u = 0; u < 4; ++u) {
                float fvj = __shfl(fvn, jg * 4 + u);     // 1 bpermute (fp32)
                float v = (fvj + fA) + tr[u];
                if (v > best) { best = v; bj = jg * 4 + u; }  // first-max
            }
            // reduce across jg groups; higher group = strictly larger j, so
            // on tie keep current (first-max). idx compare kept for safety.
            float ob = __shfl_down(best, 32); int oj = __shfl_down(bj, 32);
            if (ob > best || (ob == best && oj < bj)) { best = ob; bj = oj; }
            ob = __shfl_down(best, 16); oj = __shfl_down(bj, 16);
            if (ob > best || (ob == best && oj < bj)) { best = ob; bj = oj; }

            if (tid < 16) {
                bp[(size_t)t * 16 + i] = (unsigned char)bj;
                fvn = best;                 // ref: fv = temp.max(axis=1)
            }
            fA = fB; fB = fC;
        }
        // terminal: fv + transition[:, STOP], first-max argmax (fp32, as ref)
        float term = (tid < 16) ? fvn + trans[tid * 16 + STOP_IX] : -3.4e38f;
        int ti = tid;
#pragma unroll
        for (int off = 1; off < 16; off <<= 1) {
            float ov = __shfl_xor(term, off); int oi = __shfl_xor(ti, off);
            if (ov > term || (ov == term && oi < ti)) { term = ov; ti = oi; }
        }
        if (tid == 0) sid = ti;
    }
    __syncthreads();

    const int j = tid;
    unsigned Flo = 0x76543210u, Fhi = 0xfedcba98u;
    for (int t = 32 * j + 31; t >= 32 * j; --t) {
        uint4 g = *(const uint4*)&bp[(size_t)t * 16];
        unsigned nlo = 0, nhi = 0;
#pragma unroll
        for (int x = 0; x < 8; ++x) {
            unsigned e = (Flo >> (x * 4)) & 15u;
            nlo |= bsel16(g, e) << (x * 4);
        }
#pragma unroll
        for (int x = 0; x < 8; ++x) {
            unsigned e = (Fhi >> (x * 4)) & 15u;
            nhi |= bsel16(g, e) << (x * 4);
        }
        Flo = nlo; Fhi = nhi;
    }
    slo[j] = Flo; shi[j] = Fhi;
    slo[j + 256] = 0x76543210u; shi[j + 256] = 0xfedcba98u;
    __syncthreads();
    for (int off = 1; off < 256; off <<= 1) {
        unsigned alo = slo[j], ahi = shi[j];
        unsigned blo = slo[j + off], bhi = shi[j + off];
        __syncthreads();
        unsigned nlo = 0, nhi = 0;
#pragma unroll
        for (int x = 0; x < 8; ++x) {
            unsigned e = (blo >> (x * 4)) & 15u;
            unsigned rr = ((e < 8u ? alo : ahi) >> ((e & 7u) * 4u)) & 15u;
            nlo |= rr << (x * 4);
        }
#pragma unroll
        for (int x = 0; x < 8; ++x) {
            unsigned e = (bhi >> (x * 4)) & 15u;
            unsigned rr = ((e < 8u ? alo : ahi) >> ((e & 7u) * 4u)) & 15u;
            nhi |= rr << (x * 4);
        }
        slo[j] = nlo; shi[j] = nhi;
        __syncthreads();
    }
    int idl = sid;
    unsigned plo = slo[j + 1], phi = shi[j + 1];
    unsigned x = (((unsigned)idl < 8u ? plo : phi) >> (((unsigned)idl & 7u) * 4u)) & 15u;
    out[32 * j + 31] = (int)x;
    for (int t = 32 * j + 30; t >= 32 * j; --t) {
        x = (unsigned)bp[(size_t)(t + 1) * 16 + x];
        out[t] = (int)x;
    }
}

// ---------------------------------------------------------------------------
extern "C" void kernel_launch(void* const* d_in, const int* in_sizes, int n_in,
                              void* d_out, int out_size, void* d_ws, size_t ws_size,
                              hipStream_t stream) {
    const int*   sent  = (const int*)  d_in[0];
    const float* embed = (const float*)d_in[1];
    const float* wih_f = (const float*)d_in[2];
    const float* whh_f = (const float*)d_in[3];
    const float* bih_f = (const float*)d_in[4];
    const float* bhh_f = (const float*)d_in[5];
    const float* wih_b = (const float*)d_in[6];
    const float* whh_b = (const float*)d_in[7];
    const float* bih_b = (const float*)d_in[8];
    const float* bhh_b = (const float*)d_in[9];
    const float* Wout  = (const float*)d_in[10];
    const float* bout  = (const float*)d_in[11];
    const float* trans = (const float*)d_in[12];
    const float* h0    = (const float*)d_in[13];
    const float* c0    = (const float*)d_in[14];
    int* out = (int*)d_out;

    float* ws_xw   = (float*)d_ws;                                  // 2*T*1024 f
    float* ws_h    = ws_xw + (size_t)2 * T_LEN * G4;                // 2*T*256 f
    float* ws_feat = ws_h + (size_t)2 * T_LEN * HD;                 // T*16 f
    unsigned char* ws_bp = (unsigned char*)(ws_feat + (size_t)T_LEN * NT); // T*16 B
    unsigned long long* ws_mbox =
        (unsigned long long*)(ws_bp + (size_t)T_LEN * NT);          // 1024 u64

    // per-launch poison (replay-safe): xw + h_hist sentinel words, mbox tags
    hipMemsetAsync(ws_xw, 0xFF, (size_t)2 * T_LEN * G4 * sizeof(float), stream);
    hipMemsetAsync(ws_h, 0xFF, (size_t)2 * T_LEN * HD * sizeof(float), stream);
    hipMemsetAsync(ws_mbox, 0xFF, 1024 * sizeof(unsigned long long), stream);

    k_fused<<<256, 512, 0, stream>>>(sent, embed, wih_f, wih_b,
                                     bih_f, bhh_f, bih_b, bhh_b,
                                     whh_f, whh_b, h0, c0,
                                     ws_xw, ws_h, ws_mbox);
    k_feats<<<128, 256, 0, stream>>>(ws_h, Wout, bout, ws_feat);
    k_viterbi<<<1, 256, 0, stream>>>(ws_feat, trans, out, ws_bp);
}

// Round 15
// 13975.110 us; speedup vs baseline: 1.6806x; 1.6806x over previous
//
#include <hip/hip_runtime.h>
#include <cstdint>
#include <cstddef>

#define T_LEN 8192
#define EMB 256
#define HD 256          // hidden per direction
#define G4 1024         // 4*HD
#define NT 16
#define START_IX 14
#define STOP_IX 15

#define SLICE 8         // h outputs per WG per direction
#define ROWSD 32        // gate rows per WG per direction (4 gates x 8)
#define WPAD 260        // 1040B row stride: b128-legal + bank-balanced
#define SENT 0xFFFFFFFFu

// ---------------------------------------------------------------------------
// shared-memory union: scan state vs gemm staging (different block roles)
// ---------------------------------------------------------------------------
struct ScanS {
    float wf[ROWSD * WPAD];   // fwd weights (33280 B)
    float wb[ROWSD * WPAD];   // bwd weights
    float hf[256];
    float hb[256];
    float part[ROWSD * 17];   // partial[r][q], 17-pad -> conflict-free columns
    float xwr[16][2][32];     // xw ring: [step%16][dir][row] (4 KB)
};
struct GemmS {
    float at[32][65];
    float bt[128][65];
};
#define SMEM_BYTES 83968   // > 81920 -> exactly 1 block/CU (256 blocks = 256 CUs)

// ---------------------------------------------------------------------------
// h poll (r15): PURE agent-scope sentinel spin -- the r2/r5-proven transport.
// r14's 1.76x regression-ratio proved the mbox sc0 "fast path" NEVER hit
// (stale local-L2 line re-read; the r10 FETCH collapse was stale-hit
// absorption, not delivery). Removing it cuts ~300cy of dead probe from
// every poll iteration. Dependent-load spin paces itself at ~1 MALL RTT.
// ---------------------------------------------------------------------------
__device__ __forceinline__ unsigned poll_h(const unsigned* __restrict__ p) {
    unsigned v; int spin = 0;
    do {
        v = __hip_atomic_load(p, __ATOMIC_RELAXED, __HIP_MEMORY_SCOPE_AGENT);
    } while (v == SENT && ++spin < (1 << 20));
    return v;
}

// sentinel poll of a once-written word (xw; written by gemm filler blocks)
__device__ __forceinline__ unsigned poll_sent(const unsigned* p) {
    unsigned v; int spin = 0;
    do {
        v = __hip_atomic_load(p, __ATOMIC_RELAXED, __HIP_MEMORY_SCOPE_AGENT);
    } while (v == SENT && ++spin < (1 << 20));
    return v;
}

// ---------------------------------------------------------------------------
// Fused kernel. grid 256, block 512.  (r13 schedule; transport = pure agent.)
//  blockIdx%8 == 0 -> scan block, wsl = blockIdx>>3 (0..31): fwd+bwd slice
//  blockIdx%8 != 0 -> gemm filler computing xw (agent stores; scan reads
//                     via ring prefetch with sentinel fallback)
// Scan iteration (r11-proven 4-phase alternation; r12 proved co-phasing
// produce and poll exposes full exchange latency):
//   A: mv_f(t) | B1 | B: produce_f(t) & poll h_b(t-1) & [t%8==0: bulk xw
//      prefetch t+8..t+15] | B2 | C: mv_b(t) | B3 | D: produce_b(t) &
//      poll h_f(t) | B4
// Every poll targets data stored >=2 phases (~700+cy) earlier -> usually
// 1-2 spin samples.
// ---------------------------------------------------------------------------
__global__ __launch_bounds__(512) void k_fused(
    const int* __restrict__ sent, const float* __restrict__ embed,
    const float* __restrict__ wih_f, const float* __restrict__ wih_b,
    const float* __restrict__ bih_f, const float* __restrict__ bhh_f,
    const float* __restrict__ bih_b, const float* __restrict__ bhh_b,
    const float* __restrict__ whh_f, const float* __restrict__ whh_b,
    const float* __restrict__ h0, const float* __restrict__ c0,
    float* __restrict__ xw, float* __restrict__ h_hist)
{
    __shared__ __align__(16) char smraw[SMEM_BYTES];
    const int tid = threadIdx.x;

    if ((blockIdx.x & 7) != 0) {
        // ================= gemm filler =================
        GemmS* G = (GemmS*)smraw;
        const int f = (blockIdx.x >> 3) * 7 + (blockIdx.x & 7) - 1;  // 0..223
        const int tx = tid & 31, ty = tid >> 5;                      // 32 x 16
        for (int u = f; u < 4096; u += 224) {
            const int t_tile = u >> 4, sub = u & 15;
            const int dir = sub >> 3, r_tile = sub & 7;
            const float* __restrict__ wih = dir ? wih_b : wih_f;
            const float* __restrict__ bih = dir ? bih_b : bih_f;
            const float* __restrict__ bhh = dir ? bhh_b : bhh_f;
            const int t0 = t_tile * 32, r0 = r_tile * 128;
            float acc[2][4] = {};
            for (int k0 = 0; k0 < EMB; k0 += 64) {
                __syncthreads();   // protect staging buffers
                for (int i = tid; i < 32 * 64; i += 512) {
                    int row = i >> 6, k = i & 63;
                    int t = t0 + row;
                    int ts = dir ? (T_LEN - 1 - t) : t;
                    G->at[row][k] = embed[(size_t)sent[ts] * EMB + k0 + k];
                }
                for (int i = tid; i < 128 * 64; i += 512) {
                    int row = i >> 6, k = i & 63;
                    G->bt[row][k] = wih[(size_t)(r0 + row) * EMB + k0 + k];
                }
                __syncthreads();
#pragma unroll 16
                for (int kc = 0; kc < 64; ++kc) {
                    float a[2], b[4];
#pragma unroll
                    for (int v = 0; v < 2; ++v) a[v] = G->at[ty * 2 + v][kc];
#pragma unroll
                    for (int v = 0; v < 4; ++v) b[v] = G->bt[tx * 4 + v][kc];
#pragma unroll
                    for (int v = 0; v < 2; ++v)
#pragma unroll
                        for (int w = 0; w < 4; ++w) acc[v][w] += a[v] * b[w];
                }
            }
#pragma unroll
            for (int v = 0; v < 2; ++v) {
                int t = t0 + ty * 2 + v;
#pragma unroll
                for (int w = 0; w < 4; ++w) {
                    int r = r0 + tx * 4 + w;
                    float val = acc[v][w] + bih[r] + bhh[r];
                    __hip_atomic_store(
                        (unsigned*)&xw[((size_t)dir * T_LEN + t) * G4 + r],
                        __float_as_uint(val),
                        __ATOMIC_RELAXED, __HIP_MEMORY_SCOPE_AGENT);
                }
            }
        }
        return;
    }

    // ================= scan block =================
    ScanS* S = (ScanS*)smraw;
    const int wsl = blockIdx.x >> 3;      // 0..31
    const int wave = tid >> 6, lane = tid & 63;

    // stage both directions' weights once (33 KB each)
    for (int i = tid; i < ROWSD * 256; i += 512) {
        int r = i >> 8, k = i & 255;
        int R = ((r >> 3) << 8) + wsl * SLICE + (r & 7);
        S->wf[r * WPAD + k] = whh_f[(size_t)R * HD + k];
        S->wb[r * WPAD + k] = whh_b[(size_t)R * HD + k];
    }
    if (tid < 256) { S->hf[tid] = h0[tid]; S->hb[tid] = h0[256 + tid]; }
    float c_f = 0.f, c_b = 0.f;
    if (wave == 0 && lane < 8) {
        c_f = c0[wsl * SLICE + lane];
        c_b = c0[256 + wsl * SLICE + lane];
    }
    // xw ring init: steps 0..7 via proven agent poll (gemm runs concurrently)
    if (tid < 512) {
        int s = tid >> 6, e = tid & 63, d = e >> 5, row = e & 31;
        int R = ((row >> 3) << 8) + wsl * SLICE + (row & 7);
        unsigned v = poll_sent(
            (const unsigned*)&xw[((size_t)d * T_LEN + s) * G4 + R]);
        S->xwr[s][d][row] = __uint_as_float(v);
    }
    __syncthreads();

    float* __restrict__ hhf = h_hist;
    float* __restrict__ hhb = h_hist + (size_t)T_LEN * HD;

    for (int t = 0; t < T_LEN; ++t) {
        // ---- A: mv_f. thread (q=tid>>5 k-seg 0..15, rr=tid&31), b128 ----
        {
            const int q = tid >> 5, rr = tid & 31;
            const float4* wr = (const float4*)&S->wf[rr * WPAD + q * 16];
            const float4* hp = (const float4*)&S->hf[q * 16];
            float a0 = 0.f, a1 = 0.f, a2 = 0.f, a3 = 0.f;
#pragma unroll
            for (int i = 0; i < 4; ++i) {
                float4 wv = wr[i], hv = hp[i];
                a0 += wv.x * hv.x; a1 += wv.y * hv.y;
                a2 += wv.z * hv.z; a3 += wv.w * hv.w;
            }
            S->part[rr * 17 + q] = (a0 + a1) + (a2 + a3);
        }
        __syncthreads();   // B1

        if (wave == 0) {
            // ---- produce_f ----
            const int r = lane & 31;
            float xwv = S->xwr[t & 15][0][r];
            if (__builtin_amdgcn_ballot_w64(__float_as_uint(xwv) == SENT)) {
                int R = ((r >> 3) << 8) + wsl * SLICE + (r & 7);
                xwv = __uint_as_float(poll_sent(
                    (const unsigned*)&xw[(size_t)t * G4 + R]));
            }
            float z = xwv;
#pragma unroll
            for (int q = 0; q < 16; ++q) z += S->part[r * 17 + q];
            float a = ((r >> 3) == 2) ? tanhf(z) : 1.f / (1.f + expf(-z));
            const int j = r & 7;
            float af = __shfl(a, 8 + j);
            float ag = __shfl(a, 16 + j);
            float ao = __shfl(a, 24 + j);
            if (lane < 8) {
                c_f = af * c_f + a * ag;
                float hv = ao * tanhf(c_f);
                S->hf[wsl * SLICE + j] = hv;
                __hip_atomic_store(
                    (unsigned*)&hhf[(size_t)t * HD + wsl * SLICE + j],
                    __float_as_uint(hv),
                    __ATOMIC_RELAXED, __HIP_MEMORY_SCOPE_AGENT);
            }
        } else if (wave <= 4) {
            if (t > 0) {   // gather h_b(t-1), stored prev iter phase D
                const int idx = (wave - 1) * 64 + lane;   // 0..255
                if ((idx >> 3) != wsl) {
                    unsigned v = poll_h(
                        (const unsigned*)&hhb[(size_t)(t - 1) * HD + idx]);
                    S->hb[idx] = __uint_as_float(v);
                }
            }
        } else if (wave <= 6) {
            // bulk xw prefetch: every 8th iter, steps t+8..t+15 (plain loads,
            // drained at B2; benign-stale + sentinel-checked at consumption)
            if ((t & 7) == 0 && t + 8 < T_LEN) {
                const int base = (wave - 5) * 64 + lane;  // 0..127
#pragma unroll
                for (int u = 0; u < 4; ++u) {
                    int item = base + u * 128;            // 0..511
                    int s = item >> 6, e = item & 63;
                    int d = e >> 5, row = e & 31;
                    int step = t + 8 + s;
                    int R = ((row >> 3) << 8) + wsl * SLICE + (row & 7);
                    S->xwr[step & 15][d][row] =
                        xw[((size_t)d * T_LEN + step) * G4 + R];
                }
            }
        }
        __syncthreads();   // B2

        // ---- C: mv_b ----
        {
            const int q = tid >> 5, rr = tid & 31;
            const float4* wr = (const float4*)&S->wb[rr * WPAD + q * 16];
            const float4* hp = (const float4*)&S->hb[q * 16];
            float a0 = 0.f, a1 = 0.f, a2 = 0.f, a3 = 0.f;
#pragma unroll
            for (int i = 0; i < 4; ++i) {
                float4 wv = wr[i], hv = hp[i];
                a0 += wv.x * hv.x; a1 += wv.y * hv.y;
                a2 += wv.z * hv.z; a3 += wv.w * hv.w;
            }
            S->part[rr * 17 + q] = (a0 + a1) + (a2 + a3);
        }
        __syncthreads();   // B3

        if (wave == 0) {
            // ---- produce_b ----
            const int r = lane & 31;
            float xwv = S->xwr[t & 15][1][r];
            if (__builtin_amdgcn_ballot_w64(__float_as_uint(xwv) == SENT)) {
                int R = ((r >> 3) << 8) + wsl * SLICE + (r & 7);
                xwv = __uint_as_float(poll_sent((const unsigned*)
                    &xw[((size_t)T_LEN + t) * G4 + R]));
            }
            float z = xwv;
#pragma unroll
            for (int q = 0; q < 16; ++q) z += S->part[r * 17 + q];
            float a = ((r >> 3) == 2) ? tanhf(z) : 1.f / (1.f + expf(-z));
            const int j = r & 7;
            float af = __shfl(a, 8 + j);
            float ag = __shfl(a, 16 + j);
            float ao = __shfl(a, 24 + j);
            if (lane < 8) {
                c_b = af * c_b + a * ag;
                float hv = ao * tanhf(c_b);
                S->hb[wsl * SLICE + j] = hv;
                __hip_atomic_store(
                    (unsigned*)&hhb[(size_t)t * HD + wsl * SLICE + j],
                    __float_as_uint(hv),
                    __ATOMIC_RELAXED, __HIP_MEMORY_SCOPE_AGENT);
            }
        } else if (wave <= 4) {
            // gather h_f(t), stored this iter phase B (~2 phases earlier)
            const int idx = (wave - 1) * 64 + lane;
            if ((idx >> 3) != wsl) {
                unsigned v = poll_h(
                    (const unsigned*)&hhf[(size_t)t * HD + idx]);
                S->hf[idx] = __uint_as_float(v);
            }
        }
        __syncthreads();   // B4
    }
}

// ---------------------------------------------------------------------------
// Phase C: feats. 4-way tag split, 128 WGs. W_out staged in LDS.
// ---------------------------------------------------------------------------
__global__ __launch_bounds__(256) void k_feats(
    const float* __restrict__ h_hist, const float* __restrict__ Wout,
    const float* __restrict__ bout, float* __restrict__ feats)
{
    __shared__ float wlds[16][512];
    const int tid = threadIdx.x;
    for (int i = tid; i < 16 * 512; i += 256) wlds[i >> 9][i & 511] = Wout[i];
    __syncthreads();
    const int idx = blockIdx.x * 256 + tid;          // 0..32767
    const int t = idx >> 2, tg = (idx & 3) * 4;      // 4 tags per thread
    const float4* hf = (const float4*)(h_hist + (size_t)t * HD);
    const float4* hb = (const float4*)(h_hist + (size_t)(T_LEN + (T_LEN - 1 - t)) * HD);
    float acc[4];
#pragma unroll
    for (int g = 0; g < 4; ++g) acc[g] = bout[tg + g];
    for (int k = 0; k < 64; ++k) {
        float4 a = hf[k];
#pragma unroll
        for (int g = 0; g < 4; ++g) {
            float4 b = *(const float4*)&wlds[tg + g][k * 4];
            acc[g] += a.x * b.x + a.y * b.y + a.z * b.z + a.w * b.w;
        }
    }
    for (int k = 0; k < 64; ++k) {
        float4 a = hb[k];
#pragma unroll
        for (int g = 0; g < 4; ++g) {
            float4 b = *(const float4*)&wlds[tg + g][256 + k * 4];
            acc[g] += a.x * b.x + a.y * b.y + a.z * b.z + a.w * b.w;
        }
    }
#pragma unroll
    for (int g = 0; g < 4; ++g) feats[(size_t)t * NT + tg + g] = acc[g];
}

// ---------------------------------------------------------------------------
// Phase D: Viterbi. fp32 exact-mirror of the reference (r14, passed):
// temp[i,j] = (fv[j] + feat[i]) + trans[i,j]; fv = max_j; bp = first-max.
// Backtrack: map-composition suffix scan (proven).
// ---------------------------------------------------------------------------
__device__ __forceinline__ unsigned bsel16(uint4 g, unsigned e) {
    unsigned wd = (e < 8u) ? ((e < 4u) ? g.x : g.y) : ((e < 12u) ? g.z : g.w);
    return (wd >> ((e & 3u) * 8u)) & 15u;
}

__global__ __launch_bounds__(256) void k_viterbi(
    const float* __restrict__ feats, const float* __restrict__ trans,
    int* __restrict__ out, unsigned char* __restrict__ bp)
{
    __shared__ int sid;
    __shared__ unsigned slo[512], shi[512];
    const int tid = threadIdx.x;

    if (tid < 64) {
        const int i = tid & 15, jg = tid >> 4;
        float tr[4];
#pragma unroll
        for (int u = 0; u < 4; ++u) tr[u] = trans[i * 16 + jg * 4 + u];
        float fvn = (i == START_IX) ? 0.0f : -10000.0f;  // lanes 0-15 live
        float fA = feats[i];
        float fB = feats[16 + i];

        for (int t = 0; t < T_LEN; ++t) {
            float fC = (t + 2 < T_LEN) ? feats[(size_t)(t + 2) * NT + i] : 0.f;

            float best = -3.4e38f; int bj = 0;
#pragma unroll
            for (int u = 0; u < 4; ++u) {
                float fvj = __shfl(fvn, jg * 4 + u);     // 1 bpermute (fp32)
                float v = (fvj + fA) + tr[u];
                if (v > best) { best = v; bj = jg * 4 + u; }  // first-max
            }
            float ob = __shfl_down(best, 32); int oj = __shfl_down(bj, 32);
            if (ob > best || (ob == best && oj < bj)) { best = ob; bj = oj; }
            ob = __shfl_down(best, 16); oj = __shfl_down(bj, 16);
            if (ob > best || (ob == best && oj < bj)) { best = ob; bj = oj; }

            if (tid < 16) {
                bp[(size_t)t * 16 + i] = (unsigned char)bj;
                fvn = best;                 // ref: fv = temp.max(axis=1)
            }
            fA = fB; fB = fC;
        }
        float term = (tid < 16) ? fvn + trans[tid * 16 + STOP_IX] : -3.4e38f;
        int ti = tid;
#pragma unroll
        for (int off = 1; off < 16; off <<= 1) {
            float ov = __shfl_xor(term, off); int oi = __shfl_xor(ti, off);
            if (ov > term || (ov == term && oi < ti)) { term = ov; ti = oi; }
        }
        if (tid == 0) sid = ti;
    }
    __syncthreads();

    const int j = tid;
    unsigned Flo = 0x76543210u, Fhi = 0xfedcba98u;
    for (int t = 32 * j + 31; t >= 32 * j; --t) {
        uint4 g = *(const uint4*)&bp[(size_t)t * 16];
        unsigned nlo = 0, nhi = 0;
#pragma unroll
        for (int x = 0; x < 8; ++x) {
            unsigned e = (Flo >> (x * 4)) & 15u;
            nlo |= bsel16(g, e) << (x * 4);
        }
#pragma unroll
        for (int x = 0; x < 8; ++x) {
            unsigned e = (Fhi >> (x * 4)) & 15u;
            nhi |= bsel16(g, e) << (x * 4);
        }
        Flo = nlo; Fhi = nhi;
    }
    slo[j] = Flo; shi[j] = Fhi;
    slo[j + 256] = 0x76543210u; shi[j + 256] = 0xfedcba98u;
    __syncthreads();
    for (int off = 1; off < 256; off <<= 1) {
        unsigned alo = slo[j], ahi = shi[j];
        unsigned blo = slo[j + off], bhi = shi[j + off];
        __syncthreads();
        unsigned nlo = 0, nhi = 0;
#pragma unroll
        for (int x = 0; x < 8; ++x) {
            unsigned e = (blo >> (x * 4)) & 15u;
            unsigned rr = ((e < 8u ? alo : ahi) >> ((e & 7u) * 4u)) & 15u;
            nlo |= rr << (x * 4);
        }
#pragma unroll
        for (int x = 0; x < 8; ++x) {
            unsigned e = (bhi >> (x * 4)) & 15u;
            unsigned rr = ((e < 8u ? alo : ahi) >> ((e & 7u) * 4u)) & 15u;
            nhi |= rr << (x * 4);
        }
        slo[j] = nlo; shi[j] = nhi;
        __syncthreads();
    }
    int idl = sid;
    unsigned plo = slo[j + 1], phi = shi[j + 1];
    unsigned x = (((unsigned)idl < 8u ? plo : phi) >> (((unsigned)idl & 7u) * 4u)) & 15u;
    out[32 * j + 31] = (int)x;
    for (int t = 32 * j + 30; t >= 32 * j; --t) {
        x = (unsigned)bp[(size_t)(t + 1) * 16 + x];
        out[t] = (int)x;
    }
}

// ---------------------------------------------------------------------------
extern "C" void kernel_launch(void* const* d_in, const int* in_sizes, int n_in,
                              void* d_out, int out_size, void* d_ws, size_t ws_size,
                              hipStream_t stream) {
    const int*   sent  = (const int*)  d_in[0];
    const float* embed = (const float*)d_in[1];
    const float* wih_f = (const float*)d_in[2];
    const float* whh_f = (const float*)d_in[3];
    const float* bih_f = (const float*)d_in[4];
    const float* bhh_f = (const float*)d_in[5];
    const float* wih_b = (const float*)d_in[6];
    const float* whh_b = (const float*)d_in[7];
    const float* bih_b = (const float*)d_in[8];
    const float* bhh_b = (const float*)d_in[9];
    const float* Wout  = (const float*)d_in[10];
    const float* bout  = (const float*)d_in[11];
    const float* trans = (const float*)d_in[12];
    const float* h0    = (const float*)d_in[13];
    const float* c0    = (const float*)d_in[14];
    int* out = (int*)d_out;

    float* ws_xw   = (float*)d_ws;                                  // 2*T*1024 f
    float* ws_h    = ws_xw + (size_t)2 * T_LEN * G4;                // 2*T*256 f
    float* ws_feat = ws_h + (size_t)2 * T_LEN * HD;                 // T*16 f
    unsigned char* ws_bp = (unsigned char*)(ws_feat + (size_t)T_LEN * NT); // T*16 B

    // per-launch poison (replay-safe): xw + h_hist sentinel words
    hipMemsetAsync(ws_xw, 0xFF, (size_t)2 * T_LEN * G4 * sizeof(float), stream);
    hipMemsetAsync(ws_h, 0xFF, (size_t)2 * T_LEN * HD * sizeof(float), stream);

    k_fused<<<256, 512, 0, stream>>>(sent, embed, wih_f, wih_b,
                                     bih_f, bhh_f, bih_b, bhh_b,
                                     whh_f, whh_b, h0, c0,
                                     ws_xw, ws_h);
    k_feats<<<128, 256, 0, stream>>>(ws_h, Wout, bout, ws_feat);
    k_viterbi<<<1, 256, 0, stream>>>(ws_feat, trans, out, ws_bp);
}

// Round 16
// 13550.803 us; speedup vs baseline: 1.7332x; 1.0313x over previous
//
#include <hip/hip_runtime.h>
#include <cstdint>
#include <cstddef>

#define T_LEN 8192
#define EMB 256
#define HD 256          // hidden per direction
#define G4 1024         // 4*HD
#define NT 16
#define START_IX 14
#define STOP_IX 15

#define SLICE 8         // h outputs per WG per direction
#define ROWSD 32        // gate rows per WG per direction (4 gates x 8)
#define WPAD 260        // 1040B row stride: b128-legal + bank-balanced
#define SENT 0xFFFFFFFFu

// ---------------------------------------------------------------------------
// shared-memory union: scan state vs gemm staging (different block roles)
// ---------------------------------------------------------------------------
struct ScanS {
    float wf[ROWSD * WPAD];   // fwd weights (33280 B)
    float wb[ROWSD * WPAD];   // bwd weights
    float hf[256];
    float hb[256];
    float part[ROWSD * 17];   // partial[r][q], 17-pad -> conflict-free columns
    float xwr[16][2][32];     // xw ring: [step%16][dir][row] (4 KB)
};
struct GemmS {
    float at[32][65];
    float bt[128][65];
};
#define SMEM_BYTES 83968   // > 81920 -> exactly 1 block/CU (256 blocks = 256 CUs)

// ---------------------------------------------------------------------------
// h poll (proven r2/r5/r15): pure agent-scope sentinel spin. Dependent-load
// spin paces itself at ~1 MALL RTT; data stored >=2 phases earlier.
// ---------------------------------------------------------------------------
__device__ __forceinline__ unsigned poll_h(const unsigned* __restrict__ p) {
    unsigned v; int spin = 0;
    do {
        v = __hip_atomic_load(p, __ATOMIC_RELAXED, __HIP_MEMORY_SCOPE_AGENT);
    } while (v == SENT && ++spin < (1 << 20));
    return v;
}

// sentinel poll of a once-written word (xw; written by gemm filler blocks)
__device__ __forceinline__ unsigned poll_sent(const unsigned* p) {
    unsigned v; int spin = 0;
    do {
        v = __hip_atomic_load(p, __ATOMIC_RELAXED, __HIP_MEMORY_SCOPE_AGENT);
    } while (v == SENT && ++spin < (1 << 20));
    return v;
}

// ---------------------------------------------------------------------------
// Fused kernel. grid 256, block 512.  (unchanged from r15 -- proven 10.8ms)
//  blockIdx%8 == 0 -> scan block, wsl = blockIdx>>3 (0..31): fwd+bwd slice
//  blockIdx%8 != 0 -> gemm filler computing xw
// Scan iteration (r11-proven 4-phase alternation):
//   A: mv_f(t) | B1 | B: produce_f(t) & poll h_b(t-1) & [t%8==0: bulk xw
//      prefetch t+8..t+15] | B2 | C: mv_b(t) | B3 | D: produce_b(t) &
//      poll h_f(t) | B4
// ---------------------------------------------------------------------------
__global__ __launch_bounds__(512) void k_fused(
    const int* __restrict__ sent, const float* __restrict__ embed,
    const float* __restrict__ wih_f, const float* __restrict__ wih_b,
    const float* __restrict__ bih_f, const float* __restrict__ bhh_f,
    const float* __restrict__ bih_b, const float* __restrict__ bhh_b,
    const float* __restrict__ whh_f, const float* __restrict__ whh_b,
    const float* __restrict__ h0, const float* __restrict__ c0,
    float* __restrict__ xw, float* __restrict__ h_hist)
{
    __shared__ __align__(16) char smraw[SMEM_BYTES];
    const int tid = threadIdx.x;

    if ((blockIdx.x & 7) != 0) {
        // ================= gemm filler =================
        GemmS* G = (GemmS*)smraw;
        const int f = (blockIdx.x >> 3) * 7 + (blockIdx.x & 7) - 1;  // 0..223
        const int tx = tid & 31, ty = tid >> 5;                      // 32 x 16
        for (int u = f; u < 4096; u += 224) {
            const int t_tile = u >> 4, sub = u & 15;
            const int dir = sub >> 3, r_tile = sub & 7;
            const float* __restrict__ wih = dir ? wih_b : wih_f;
            const float* __restrict__ bih = dir ? bih_b : bih_f;
            const float* __restrict__ bhh = dir ? bhh_b : bhh_f;
            const int t0 = t_tile * 32, r0 = r_tile * 128;
            float acc[2][4] = {};
            for (int k0 = 0; k0 < EMB; k0 += 64) {
                __syncthreads();   // protect staging buffers
                for (int i = tid; i < 32 * 64; i += 512) {
                    int row = i >> 6, k = i & 63;
                    int t = t0 + row;
                    int ts = dir ? (T_LEN - 1 - t) : t;
                    G->at[row][k] = embed[(size_t)sent[ts] * EMB + k0 + k];
                }
                for (int i = tid; i < 128 * 64; i += 512) {
                    int row = i >> 6, k = i & 63;
                    G->bt[row][k] = wih[(size_t)(r0 + row) * EMB + k0 + k];
                }
                __syncthreads();
#pragma unroll 16
                for (int kc = 0; kc < 64; ++kc) {
                    float a[2], b[4];
#pragma unroll
                    for (int v = 0; v < 2; ++v) a[v] = G->at[ty * 2 + v][kc];
#pragma unroll
                    for (int v = 0; v < 4; ++v) b[v] = G->bt[tx * 4 + v][kc];
#pragma unroll
                    for (int v = 0; v < 2; ++v)
#pragma unroll
                        for (int w = 0; w < 4; ++w) acc[v][w] += a[v] * b[w];
                }
            }
#pragma unroll
            for (int v = 0; v < 2; ++v) {
                int t = t0 + ty * 2 + v;
#pragma unroll
                for (int w = 0; w < 4; ++w) {
                    int r = r0 + tx * 4 + w;
                    float val = acc[v][w] + bih[r] + bhh[r];
                    __hip_atomic_store(
                        (unsigned*)&xw[((size_t)dir * T_LEN + t) * G4 + r],
                        __float_as_uint(val),
                        __ATOMIC_RELAXED, __HIP_MEMORY_SCOPE_AGENT);
                }
            }
        }
        return;
    }

    // ================= scan block =================
    ScanS* S = (ScanS*)smraw;
    const int wsl = blockIdx.x >> 3;      // 0..31
    const int wave = tid >> 6, lane = tid & 63;

    // stage both directions' weights once (33 KB each)
    for (int i = tid; i < ROWSD * 256; i += 512) {
        int r = i >> 8, k = i & 255;
        int R = ((r >> 3) << 8) + wsl * SLICE + (r & 7);
        S->wf[r * WPAD + k] = whh_f[(size_t)R * HD + k];
        S->wb[r * WPAD + k] = whh_b[(size_t)R * HD + k];
    }
    if (tid < 256) { S->hf[tid] = h0[tid]; S->hb[tid] = h0[256 + tid]; }
    float c_f = 0.f, c_b = 0.f;
    if (wave == 0 && lane < 8) {
        c_f = c0[wsl * SLICE + lane];
        c_b = c0[256 + wsl * SLICE + lane];
    }
    // xw ring init: steps 0..7 via proven agent poll (gemm runs concurrently)
    if (tid < 512) {
        int s = tid >> 6, e = tid & 63, d = e >> 5, row = e & 31;
        int R = ((row >> 3) << 8) + wsl * SLICE + (row & 7);
        unsigned v = poll_sent(
            (const unsigned*)&xw[((size_t)d * T_LEN + s) * G4 + R]);
        S->xwr[s][d][row] = __uint_as_float(v);
    }
    __syncthreads();

    float* __restrict__ hhf = h_hist;
    float* __restrict__ hhb = h_hist + (size_t)T_LEN * HD;

    for (int t = 0; t < T_LEN; ++t) {
        // ---- A: mv_f. thread (q=tid>>5 k-seg 0..15, rr=tid&31), b128 ----
        {
            const int q = tid >> 5, rr = tid & 31;
            const float4* wr = (const float4*)&S->wf[rr * WPAD + q * 16];
            const float4* hp = (const float4*)&S->hf[q * 16];
            float a0 = 0.f, a1 = 0.f, a2 = 0.f, a3 = 0.f;
#pragma unroll
            for (int i = 0; i < 4; ++i) {
                float4 wv = wr[i], hv = hp[i];
                a0 += wv.x * hv.x; a1 += wv.y * hv.y;
                a2 += wv.z * hv.z; a3 += wv.w * hv.w;
            }
            S->part[rr * 17 + q] = (a0 + a1) + (a2 + a3);
        }
        __syncthreads();   // B1

        if (wave == 0) {
            // ---- produce_f ----
            const int r = lane & 31;
            float xwv = S->xwr[t & 15][0][r];
            if (__builtin_amdgcn_ballot_w64(__float_as_uint(xwv) == SENT)) {
                int R = ((r >> 3) << 8) + wsl * SLICE + (r & 7);
                xwv = __uint_as_float(poll_sent(
                    (const unsigned*)&xw[(size_t)t * G4 + R]));
            }
            float z = xwv;
#pragma unroll
            for (int q = 0; q < 16; ++q) z += S->part[r * 17 + q];
            float a = ((r >> 3) == 2) ? tanhf(z) : 1.f / (1.f + expf(-z));
            const int j = r & 7;
            float af = __shfl(a, 8 + j);
            float ag = __shfl(a, 16 + j);
            float ao = __shfl(a, 24 + j);
            if (lane < 8) {
                c_f = af * c_f + a * ag;
                float hv = ao * tanhf(c_f);
                S->hf[wsl * SLICE + j] = hv;
                __hip_atomic_store(
                    (unsigned*)&hhf[(size_t)t * HD + wsl * SLICE + j],
                    __float_as_uint(hv),
                    __ATOMIC_RELAXED, __HIP_MEMORY_SCOPE_AGENT);
            }
        } else if (wave <= 4) {
            if (t > 0) {   // gather h_b(t-1), stored prev iter phase D
                const int idx = (wave - 1) * 64 + lane;   // 0..255
                if ((idx >> 3) != wsl) {
                    unsigned v = poll_h(
                        (const unsigned*)&hhb[(size_t)(t - 1) * HD + idx]);
                    S->hb[idx] = __uint_as_float(v);
                }
            }
        } else if (wave <= 6) {
            // bulk xw prefetch: every 8th iter, steps t+8..t+15 (plain loads,
            // drained at B2; benign-stale + sentinel-checked at consumption)
            if ((t & 7) == 0 && t + 8 < T_LEN) {
                const int base = (wave - 5) * 64 + lane;  // 0..127
#pragma unroll
                for (int u = 0; u < 4; ++u) {
                    int item = base + u * 128;            // 0..511
                    int s = item >> 6, e = item & 63;
                    int d = e >> 5, row = e & 31;
                    int step = t + 8 + s;
                    int R = ((row >> 3) << 8) + wsl * SLICE + (row & 7);
                    S->xwr[step & 15][d][row] =
                        xw[((size_t)d * T_LEN + step) * G4 + R];
                }
            }
        }
        __syncthreads();   // B2

        // ---- C: mv_b ----
        {
            const int q = tid >> 5, rr = tid & 31;
            const float4* wr = (const float4*)&S->wb[rr * WPAD + q * 16];
            const float4* hp = (const float4*)&S->hb[q * 16];
            float a0 = 0.f, a1 = 0.f, a2 = 0.f, a3 = 0.f;
#pragma unroll
            for (int i = 0; i < 4; ++i) {
                float4 wv = wr[i], hv = hp[i];
                a0 += wv.x * hv.x; a1 += wv.y * hv.y;
                a2 += wv.z * hv.z; a3 += wv.w * hv.w;
            }
            S->part[rr * 17 + q] = (a0 + a1) + (a2 + a3);
        }
        __syncthreads();   // B3

        if (wave == 0) {
            // ---- produce_b ----
            const int r = lane & 31;
            float xwv = S->xwr[t & 15][1][r];
            if (__builtin_amdgcn_ballot_w64(__float_as_uint(xwv) == SENT)) {
                int R = ((r >> 3) << 8) + wsl * SLICE + (r & 7);
                xwv = __uint_as_float(poll_sent((const unsigned*)
                    &xw[((size_t)T_LEN + t) * G4 + R]));
            }
            float z = xwv;
#pragma unroll
            for (int q = 0; q < 16; ++q) z += S->part[r * 17 + q];
            float a = ((r >> 3) == 2) ? tanhf(z) : 1.f / (1.f + expf(-z));
            const int j = r & 7;
            float af = __shfl(a, 8 + j);
            float ag = __shfl(a, 16 + j);
            float ao = __shfl(a, 24 + j);
            if (lane < 8) {
                c_b = af * c_b + a * ag;
                float hv = ao * tanhf(c_b);
                S->hb[wsl * SLICE + j] = hv;
                __hip_atomic_store(
                    (unsigned*)&hhb[(size_t)t * HD + wsl * SLICE + j],
                    __float_as_uint(hv),
                    __ATOMIC_RELAXED, __HIP_MEMORY_SCOPE_AGENT);
            }
        } else if (wave <= 4) {
            // gather h_f(t), stored this iter phase B (~2 phases earlier)
            const int idx = (wave - 1) * 64 + lane;
            if ((idx >> 3) != wsl) {
                unsigned v = poll_h(
                    (const unsigned*)&hhf[(size_t)t * HD + idx]);
                S->hf[idx] = __uint_as_float(v);
            }
        }
        __syncthreads();   // B4
    }
}

// ---------------------------------------------------------------------------
// Phase C: feats. 4-way tag split, 128 WGs. W_out staged in LDS.
// ---------------------------------------------------------------------------
__global__ __launch_bounds__(256) void k_feats(
    const float* __restrict__ h_hist, const float* __restrict__ Wout,
    const float* __restrict__ bout, float* __restrict__ feats)
{
    __shared__ float wlds[16][512];
    const int tid = threadIdx.x;
    for (int i = tid; i < 16 * 512; i += 256) wlds[i >> 9][i & 511] = Wout[i];
    __syncthreads();
    const int idx = blockIdx.x * 256 + tid;          // 0..32767
    const int t = idx >> 2, tg = (idx & 3) * 4;      // 4 tags per thread
    const float4* hf = (const float4*)(h_hist + (size_t)t * HD);
    const float4* hb = (const float4*)(h_hist + (size_t)(T_LEN + (T_LEN - 1 - t)) * HD);
    float acc[4];
#pragma unroll
    for (int g = 0; g < 4; ++g) acc[g] = bout[tg + g];
    for (int k = 0; k < 64; ++k) {
        float4 a = hf[k];
#pragma unroll
        for (int g = 0; g < 4; ++g) {
            float4 b = *(const float4*)&wlds[tg + g][k * 4];
            acc[g] += a.x * b.x + a.y * b.y + a.z * b.z + a.w * b.w;
        }
    }
    for (int k = 0; k < 64; ++k) {
        float4 a = hb[k];
#pragma unroll
        for (int g = 0; g < 4; ++g) {
            float4 b = *(const float4*)&wlds[tg + g][256 + k * 4];
            acc[g] += a.x * b.x + a.y * b.y + a.z * b.z + a.w * b.w;
        }
    }
#pragma unroll
    for (int g = 0; g < 4; ++g) feats[(size_t)t * NT + tg + g] = acc[g];
}

// ---------------------------------------------------------------------------
// Phase D: Viterbi. r16: feats fed through an LDS double buffer — wave 0
// scans 256 steps from buf[b] while waves 1-3 bulk-load the next 256x16
// chunk (16 KB, coalesced) into buf[b^1]; one barrier per chunk. Removes
// the per-step MALL-latency feats load stall (~200-500cy/step) that made
// the tail invariant across three fv rewrites. Arithmetic unchanged from
// r14/r15 (fp32 exact-mirror of the reference; absmax 0 proven).
// ---------------------------------------------------------------------------
__device__ __forceinline__ unsigned bsel16(uint4 g, unsigned e) {
    unsigned wd = (e < 8u) ? ((e < 4u) ? g.x : g.y) : ((e < 12u) ? g.z : g.w);
    return (wd >> ((e & 3u) * 8u)) & 15u;
}

__global__ __launch_bounds__(256) void k_viterbi(
    const float* __restrict__ feats, const float* __restrict__ trans,
    int* __restrict__ out, unsigned char* __restrict__ bp)
{
    __shared__ int sid;
    __shared__ unsigned slo[512], shi[512];
    __shared__ float fbuf[2][256][16];    // 32 KB feats double buffer
    const int tid = threadIdx.x;
    const int wave = tid >> 6, lane = tid & 63;
    const int i = tid & 15, jg = lane >> 4;

    // prologue: all threads fill buf0 with steps 0..255 (coalesced)
    for (int idx = tid; idx < 4096; idx += 256)
        fbuf[0][idx >> 4][idx & 15] = feats[idx];

    float tr[4];
    if (tid < 64) {
#pragma unroll
        for (int u = 0; u < 4; ++u) tr[u] = trans[i * 16 + jg * 4 + u];
    }
    float fvn = (i == START_IX) ? 0.0f : -10000.0f;   // live in w0 lanes 0-15
    __syncthreads();

    for (int chunk = 0; chunk < T_LEN / 256; ++chunk) {
        const int b = chunk & 1;
        const int base = chunk * 256;
        if (wave == 0) {
            float fA = fbuf[b][0][i];
            float fB = fbuf[b][1][i];
            for (int s = 0; s < 256; ++s) {
                float fC = (s + 2 < 256) ? fbuf[b][s + 2][i] : 0.f;

                float best = -3.4e38f; int bj = 0;
#pragma unroll
                for (int u = 0; u < 4; ++u) {
                    float fvj = __shfl(fvn, jg * 4 + u);   // 1 bpermute (fp32)
                    float v = (fvj + fA) + tr[u];
                    if (v > best) { best = v; bj = jg * 4 + u; }  // first-max
                }
                float ob = __shfl_down(best, 32); int oj = __shfl_down(bj, 32);
                if (ob > best || (ob == best && oj < bj)) { best = ob; bj = oj; }
                ob = __shfl_down(best, 16); oj = __shfl_down(bj, 16);
                if (ob > best || (ob == best && oj < bj)) { best = ob; bj = oj; }

                if (lane < 16) {
                    bp[(size_t)(base + s) * 16 + i] = (unsigned char)bj;
                    fvn = best;             // ref: fv = temp.max(axis=1)
                }
                fA = fB; fB = fC;
            }
        } else if (chunk + 1 < T_LEN / 256) {
            // waves 1-3: fill next buffer with steps base+256 .. base+511
            const int nb = b ^ 1;
            const size_t noff = (size_t)(base + 256) * 16;
            for (int idx = (wave - 1) * 64 + lane; idx < 4096; idx += 192)
                fbuf[nb][idx >> 4][idx & 15] = feats[noff + idx];
        }
        __syncthreads();
    }

    // terminal: fv + transition[:, STOP], first-max argmax (fp32, as ref)
    if (tid < 64) {
        float term = (tid < 16) ? fvn + trans[tid * 16 + STOP_IX] : -3.4e38f;
        int ti = tid;
#pragma unroll
        for (int off = 1; off < 16; off <<= 1) {
            float ov = __shfl_xor(term, off); int oi = __shfl_xor(ti, off);
            if (ov > term || (ov == term && oi < ti)) { term = ov; ti = oi; }
        }
        if (tid == 0) sid = ti;
    }
    __syncthreads();

    // backtrack: map-composition suffix scan (proven)
    const int j = tid;
    unsigned Flo = 0x76543210u, Fhi = 0xfedcba98u;
    for (int t = 32 * j + 31; t >= 32 * j; --t) {
        uint4 g = *(const uint4*)&bp[(size_t)t * 16];
        unsigned nlo = 0, nhi = 0;
#pragma unroll
        for (int x = 0; x < 8; ++x) {
            unsigned e = (Flo >> (x * 4)) & 15u;
            nlo |= bsel16(g, e) << (x * 4);
        }
#pragma unroll
        for (int x = 0; x < 8; ++x) {
            unsigned e = (Fhi >> (x * 4)) & 15u;
            nhi |= bsel16(g, e) << (x * 4);
        }
        Flo = nlo; Fhi = nhi;
    }
    slo[j] = Flo; shi[j] = Fhi;
    slo[j + 256] = 0x76543210u; shi[j + 256] = 0xfedcba98u;
    __syncthreads();
    for (int off = 1; off < 256; off <<= 1) {
        unsigned alo = slo[j], ahi = shi[j];
        unsigned blo = slo[j + off], bhi = shi[j + off];
        __syncthreads();
        unsigned nlo = 0, nhi = 0;
#pragma unroll
        for (int x = 0; x < 8; ++x) {
            unsigned e = (blo >> (x * 4)) & 15u;
            unsigned rr = ((e < 8u ? alo : ahi) >> ((e & 7u) * 4u)) & 15u;
            nlo |= rr << (x * 4);
        }
#pragma unroll
        for (int x = 0; x < 8; ++x) {
            unsigned e = (bhi >> (x * 4)) & 15u;
            unsigned rr = ((e < 8u ? alo : ahi) >> ((e & 7u) * 4u)) & 15u;
            nhi |= rr << (x * 4);
        }
        slo[j] = nlo; shi[j] = nhi;
        __syncthreads();
    }
    int idl = sid;
    unsigned plo = slo[j + 1], phi = shi[j + 1];
    unsigned x = (((unsigned)idl < 8u ? plo : phi) >> (((unsigned)idl & 7u) * 4u)) & 15u;
    out[32 * j + 31] = (int)x;
    for (int t = 32 * j + 30; t >= 32 * j; --t) {
        x = (unsigned)bp[(size_t)(t + 1) * 16 + x];
        out[t] = (int)x;
    }
}

// ---------------------------------------------------------------------------
extern "C" void kernel_launch(void* const* d_in, const int* in_sizes, int n_in,
                              void* d_out, int out_size, void* d_ws, size_t ws_size,
                              hipStream_t stream) {
    const int*   sent  = (const int*)  d_in[0];
    const float* embed = (const float*)d_in[1];
    const float* wih_f = (const float*)d_in[2];
    const float* whh_f = (const float*)d_in[3];
    const float* bih_f = (const float*)d_in[4];
    const float* bhh_f = (const float*)d_in[5];
    const float* wih_b = (const float*)d_in[6];
    const float* whh_b = (const float*)d_in[7];
    const float* bih_b = (const float*)d_in[8];
    const float* bhh_b = (const float*)d_in[9];
    const float* Wout  = (const float*)d_in[10];
    const float* bout  = (const float*)d_in[11];
    const float* trans = (const float*)d_in[12];
    const float* h0    = (const float*)d_in[13];
    const float* c0    = (const float*)d_in[14];
    int* out = (int*)d_out;

    float* ws_xw   = (float*)d_ws;                                  // 2*T*1024 f
    float* ws_h    = ws_xw + (size_t)2 * T_LEN * G4;                // 2*T*256 f
    float* ws_feat = ws_h + (size_t)2 * T_LEN * HD;                 // T*16 f
    unsigned char* ws_bp = (unsigned char*)(ws_feat + (size_t)T_LEN * NT); // T*16 B

    // per-launch poison (replay-safe): xw + h_hist sentinel words
    hipMemsetAsync(ws_xw, 0xFF, (size_t)2 * T_LEN * G4 * sizeof(float), stream);
    hipMemsetAsync(ws_h, 0xFF, (size_t)2 * T_LEN * HD * sizeof(float), stream);

    k_fused<<<256, 512, 0, stream>>>(sent, embed, wih_f, wih_b,
                                     bih_f, bhh_f, bih_b, bhh_b,
                                     whh_f, whh_b, h0, c0,
                                     ws_xw, ws_h);
    k_feats<<<128, 256, 0, stream>>>(ws_h, Wout, bout, ws_feat);
    k_viterbi<<<1, 256, 0, stream>>>(ws_feat, trans, out, ws_bp);
}